// Round 13
// baseline (431.465 us; speedup 1.0000x reference)
//
#include <hip/hip_runtime.h>
#include <hip/hip_bf16.h>
#include <math.h>

typedef __attribute__((ext_vector_type(8))) short bf16x8;
typedef __attribute__((ext_vector_type(16))) float f32x16;

__device__ __forceinline__ float sigf(float x) { return 1.0f / (1.0f + expf(-x)); }
// P-layout swizzle: fold byte bits 9,10,13 into bank bits 4,5,6 (bijective per 16B granule)
__device__ __forceinline__ int swz(int b) { return b ^ ((b >> 5) & 0x30) ^ ((b >> 7) & 0x40); }

// prep: taT2[b][j][c][i] (bf16), h (f32), hTg (bf16 [b][v][i]), msk,
//       W2FTB blocked, transposed small weights, zero cnt[192].
// grid = 2048 (b = bid>>5, j = bid&31) x 256 thr.
__global__ __launch_bounds__(256, 4) void k_prep(
    const float* __restrict__ edge, const float* __restrict__ adj,
    const float* __restrict__ W1, const float* __restrict__ b1,
    const float* __restrict__ x, const float* __restrict__ W_emb,
    const float* __restrict__ b_emb, const float* __restrict__ W2,
    const float* __restrict__ gWi, const float* __restrict__ gWh,
    const float* __restrict__ b2, const float* __restrict__ lWi,
    const float* __restrict__ lWh,
    __hip_bfloat16* __restrict__ taT2, __hip_bfloat16* __restrict__ W2FTB,
    float* __restrict__ h, short* __restrict__ hTg, float* __restrict__ msk,
    float* __restrict__ gWiT, float* __restrict__ gWhT, float* __restrict__ b2T,
    float* __restrict__ lWiT, float* __restrict__ lWhT, int* __restrict__ cnt) {
    __shared__ float es[512];       // [i][k] 32x16
    __shared__ float adjv[32];
    __shared__ float xs[256];
    __shared__ short t_lds[4096];   // [c][i]
    const int tid = threadIdx.x, bid = blockIdx.x;
    const int b = bid >> 5, j = bid & 31;
    const int c = tid & 127, g = tid >> 7;
    float wr[16];
    #pragma unroll
    for (int v = 0; v < 16; ++v) wr[v] = W1[v * 128 + c];
    const float b1c = b1[c];
    if (tid < 128) {
        int i = tid >> 2, k4 = tid & 3;
        ((float4*)es)[tid] = *(const float4*)&edge[(((long)(b * 32 + i)) * 32 + j) * 16 + k4 * 4];
    } else if (tid < 160) {
        int i = tid - 128;
        adjv[i] = adj[(b * 32 + i) * 32 + j];
    }
    if (bid < 256) xs[tid] = x[bid * 256 + tid];
    __syncthreads();
    {   // edge MLP for i = g*16 .. +15, col c -> t_lds[c][i]
        #pragma unroll
        for (int ii = 0; ii < 16; ++ii) {
            int i = g * 16 + ii;
            const float* er = es + i * 16;
            float acc = b1c;
            #pragma unroll
            for (int k = 0; k < 16; ++k) acc += er[k] * wr[k];
            float val = adjv[i] * fmaxf(acc, 0.f);
            t_lds[c * 32 + i] = (short)__bfloat16_as_ushort(__float2bfloat16(val));
        }
    }
    __syncthreads();
    {   // coalesced copy out
        int4* dst = (int4*)(taT2 + (long)bid * 4096);
        const int4* src = (const int4*)t_lds;
        dst[tid] = src[tid];
        dst[tid + 256] = src[tid + 256];
    }
    if (bid < 256) {            // embed: 8 rows of (b*N+n)
        int r = tid >> 5, u = tid & 31;
        int rowe = bid * 8 + r;
        float acc = b_emb[u];
        #pragma unroll
        for (int k = 0; k < 32; ++k) acc += xs[r * 32 + k] * W_emb[k * 32 + u];
        h[rowe * 32 + u] = acc;
        hTg[(rowe >> 5) * 1024 + u * 32 + (rowe & 31)] =
            (short)__bfloat16_as_ushort(__float2bfloat16(acc));
        if (u == 0) {
            float s = 0.f;
            #pragma unroll
            for (int k = 0; k < 32; ++k) s += xs[r * 32 + k];
            msk[rowe] = (s > 0.f) ? 1.f : 0.f;
        }
    } else if (bid < 384) {     // W2FTB
        int base = (bid - 256) * 1024;
        #pragma unroll
        for (int q = 0; q < 4; ++q) {
            int idx = base + q * 256 + tid;
            int chunk = idx >> 9, u = (idx >> 4) & 31, inner = idx & 15;
            int cv = chunk * 16 + inner;
            int cc = cv >> 5, v = cv & 31;
            W2FTB[idx] = __float2bfloat16(W2[cc * 1024 + u * 32 + v]);
        }
    } else if (bid == 384) {    // transposed weights
        for (int idx = tid; idx < 3072; idx += 256) gWiT[(idx & 31) * 96 + (idx >> 5)] = gWi[idx];
        for (int idx = tid; idx < 3072; idx += 256) gWhT[(idx & 31) * 96 + (idx >> 5)] = gWh[idx];
        for (int idx = tid; idx < 1024; idx += 256) b2T[(idx & 31) * 32 + (idx >> 5)] = b2[idx];
        for (int idx = tid; idx < 8192; idx += 256) lWiT[(idx & 63) * 128 + (idx >> 6)] = lWi[idx];
        for (int idx = tid; idx < 4096; idx += 256) lWhT[(idx & 31) * 128 + (idx >> 5)] = lWh[idx];
    } else if (bid == 385) {
        if (tid < 192) cnt[tid] = 0;
    }
}

// one layer: grid 256 = (b = bid>>2, cq = bid&3) x 256 thr (4 waves).
// GEMM1 -> P LDS (swizzled), GEMM2 -> 4-wave reduce -> partial; last block per b
// (via device-scope counter) does GRU (+ Set2Set/fc when final_).
__global__ __launch_bounds__(256, 2) void k_layer(
    const __hip_bfloat16* __restrict__ taT2, const __hip_bfloat16* __restrict__ W2FTB,
    float* __restrict__ hG, short* __restrict__ hTg,
    const float* __restrict__ adj, const float* __restrict__ msk,
    const float* __restrict__ gWiT, const float* __restrict__ gWhT,
    const float* __restrict__ b2T, const float* __restrict__ gbi,
    const float* __restrict__ gbh,
    const float* __restrict__ lWiT, const float* __restrict__ lWhT,
    const float* __restrict__ lbi, const float* __restrict__ lbh,
    const float* __restrict__ Wf, const float* __restrict__ bf,
    float* __restrict__ partial, int* __restrict__ cnt,
    float* __restrict__ out, int final_) {
    __shared__ __align__(16) char P_lds[65536];
    __shared__ __align__(16) short hT[1024];      // [v][i]
    __shared__ float hsh[1024], adjs[1024];
    __shared__ float mskk[32];
    __shared__ int last_flag;
    const int tid = threadIdx.x, bid = blockIdx.x;
    const int b = bid >> 2, cq = bid & 3;
    const int w = tid >> 6, l = tid & 63, lid = l & 31, kh = l >> 5;

    if (tid < 128) ((int4*)hT)[tid] = ((const int4*)(hTg + b * 1024))[tid];
    __syncthreads();
    const short* taB = (const short*)taT2 + (long)b * 131072;
    const short* w2b = (const short*)W2FTB;
    const short* hTp = hT + lid * 32 + kh * 8;
    bf16x8 hb0 = *(const bf16x8*)hTp;          // B: col=v=lid, k=i=kh*8+e
    bf16x8 hb1 = *(const bf16x8*)(hTp + 16);
    // ---- GEMM1: wave w computes j = w*8 .. +7 ----
    #pragma unroll 2
    for (int q = 0; q < 8; ++q) {
        int jj = w * 8 + q;
        const short* ap = taB + (jj * 128 + cq * 32 + lid) * 32 + kh * 8;
        bf16x8 a0 = *(const bf16x8*)ap;
        bf16x8 a1 = *(const bf16x8*)(ap + 16);
        f32x16 accg = {};
        accg = __builtin_amdgcn_mfma_f32_32x32x16_bf16(a0, hb0, accg, 0, 0, 0);
        accg = __builtin_amdgcn_mfma_f32_32x32x16_bf16(a1, hb1, accg, 0, 0, 0);
        #pragma unroll
        for (int r = 0; r < 16; ++r) {
            int crow = (r & 3) + 8 * (r >> 2) + 4 * kh;   // clocal
            int byte = (crow * 2 + (lid >> 4)) * 1024 + ((lid >> 3) & 1) * 512
                     + jj * 16 + (lid & 7) * 2;
            *(short*)(P_lds + swz(byte)) =
                (short)__bfloat16_as_ushort(__float2bfloat16(accg[r]));
        }
    }
    __syncthreads();
    // ---- GEMM2: wave w covers slices w*16 .. +15 ----
    f32x16 acc = {};
    #pragma unroll
    for (int kk = 0; kk < 16; ++kk) {
        int slice = w * 16 + kk;
        bf16x8 a = *(const bf16x8*)(P_lds + swz(slice * 1024 + kh * 512 + lid * 16));
        bf16x8 bg = *(const bf16x8*)(w2b + (cq * 64 + slice) * 512 + lid * 16 + kh * 8);
        acc = __builtin_amdgcn_mfma_f32_32x32x16_bf16(a, bg, acc, 0, 0, 0);
    }
    __syncthreads();
    {   // 4-wave reduce via red[4][1024] (aliases P_lds)
        float* red = (float*)P_lds + w * 1024;
        #pragma unroll
        for (int r = 0; r < 16; ++r) {
            int crow = (r & 3) + 8 * (r >> 2) + 4 * kh;   // = j
            red[crow * 32 + lid] = acc[r];
        }
    }
    __syncthreads();
    {
        float* r0 = (float*)P_lds;
        for (int k = tid; k < 1024; k += 256)
            partial[(long)bid * 1024 + k] = r0[k] + r0[1024 + k] + r0[2048 + k] + r0[3072 + k];
    }
    __threadfence();
    __syncthreads();
    if (tid == 0) {
        int old = __hip_atomic_fetch_add(&cnt[b], 1, __ATOMIC_ACQ_REL, __HIP_MEMORY_SCOPE_AGENT);
        last_flag = (old == 3);
    }
    __syncthreads();
    if (!last_flag) return;
    __threadfence();
    // ======== last block of b: GRU over all 32 j (4 passes) ========
    float* wWiT  = (float*)(P_lds + 24576);   // [v*96+k]
    float* wWhT  = (float*)(P_lds + 36864);
    float* b2s   = (float*)(P_lds + 49152);   // [v*32+u]
    float* hsumL = (float*)(P_lds + 16384);
    float* mLs   = (float*)(P_lds + 20480);
    float* sA    = (float*)(P_lds + 53248);   // S2S aux
    for (int idx = tid; idx < 3072; idx += 256) { wWiT[idx] = gWiT[idx]; wWhT[idx] = gWhT[idx]; }
    for (int idx = tid; idx < 1024; idx += 256) {
        b2s[idx] = b2T[idx];
        hsh[idx] = hG[b * 1024 + idx];
        adjs[idx] = adj[b * 1024 + idx];
    }
    if (tid < 32) mskk[tid] = msk[b * 32 + tid];
    float ps[4];
    #pragma unroll
    for (int p = 0; p < 4; ++p) {
        float s = 0.f;
        #pragma unroll
        for (int cqq = 0; cqq < 4; ++cqq)
            s += partial[((long)(b * 4 + cqq)) * 1024 + p * 256 + tid];
        ps[p] = s;
    }
    __syncthreads();
    const int j8 = tid >> 5, u = tid & 31;
    #pragma unroll
    for (int p = 0; p < 4; ++p) {
        int j = j8 + p * 8;
        float hs = 0.f;
        #pragma unroll
        for (int i = 0; i < 32; ++i) hs += adjs[i * 32 + j] * hsh[i * 32 + u];
        hsumL[j * 32 + u] = hs;
    }
    __syncthreads();
    #pragma unroll
    for (int p = 0; p < 4; ++p) {
        int j = j8 + p * 8;
        float m = ps[p];
        #pragma unroll
        for (int v = 0; v < 32; ++v) m += b2s[v * 32 + u] * hsumL[j * 32 + v];
        mLs[j * 32 + u] = m;
    }
    __syncthreads();
    float res[4];
    #pragma unroll
    for (int p = 0; p < 4; ++p) {
        int j = j8 + p * 8;
        float gi[3], gh[3];
        #pragma unroll
        for (int kb = 0; kb < 3; ++kb) {
            int k = kb * 32 + u;
            float a = gbi[k], cgh = gbh[k];
            #pragma unroll
            for (int v = 0; v < 32; ++v) {
                a   += mLs[j * 32 + v] * wWiT[v * 96 + k];
                cgh += hsh[j * 32 + v] * wWhT[v * 96 + k];
            }
            gi[kb] = a; gh[kb] = cgh;
        }
        float r = sigf(gi[0] + gh[0]);
        float z = sigf(gi[1] + gh[1]);
        float n = tanhf(gi[2] + r * gh[2]);
        float hv = hsh[j * 32 + u];
        res[p] = mskk[j] * ((1.f - z) * n + z * hv);
    }
    __syncthreads();
    #pragma unroll
    for (int p = 0; p < 4; ++p) {
        int j = j8 + p * 8;
        hsh[j * 32 + u] = res[p];
        hG[b * 1024 + j * 32 + u] = res[p];
        hTg[b * 1024 + u * 32 + j] = (short)__bfloat16_as_ushort(__float2bfloat16(res[p]));
    }
    __syncthreads();
    if (!final_) return;
    // ================= Set2Set + final fc =================
    float* qs = sA; float* cs2 = sA + 32; float* qstar = sA + 64;
    float* gsv = sA + 128; float* asv = sA + 256;
    if (tid < 64) { qstar[tid] = 0.f; if (tid < 32) { qs[tid] = 0.f; cs2[tid] = 0.f; } }
    __syncthreads();
    for (int step = 0; step < 3; ++step) {
        if (tid < 128) {
            float g = lbi[tid] + lbh[tid];
            #pragma unroll
            for (int pp = 0; pp < 64; ++pp) g += qstar[pp] * lWiT[pp * 128 + tid];
            #pragma unroll
            for (int v = 0; v < 32; ++v) g += qs[v] * lWhT[v * 128 + tid];
            gsv[tid] = g;
        }
        __syncthreads();
        if (tid < 32) {
            float ci = sigf(gsv[32 + tid]) * cs2[tid] + sigf(gsv[tid]) * tanhf(gsv[64 + tid]);
            cs2[tid] = ci;
            qs[tid] = sigf(gsv[96 + tid]) * tanhf(ci);
        }
        __syncthreads();
        if (tid < 32) {
            float e = 0.f;
            #pragma unroll
            for (int v = 0; v < 32; ++v) e += hsh[tid * 32 + v] * qs[v];
            e = (mskk[tid] == 0.f) ? -INFINITY : e;
            float mx = e;
            for (int o = 16; o >= 1; o >>= 1) mx = fmaxf(mx, __shfl_xor(mx, o, 64));
            float a = expf(e - mx);
            float ss = a;
            for (int o = 16; o >= 1; o >>= 1) ss += __shfl_xor(ss, o, 64);
            asv[tid] = a / ss;
        }
        __syncthreads();
        if (tid < 32) {
            float rr = 0.f;
            #pragma unroll
            for (int nn = 0; nn < 32; ++nn) rr += asv[nn] * hsh[nn * 32 + tid] * mskk[nn];
            qstar[tid] = qs[tid];
            qstar[32 + tid] = rr;
        }
        __syncthreads();
    }
    if (tid < 64) {
        float v = qstar[tid] * Wf[tid];
        for (int o = 32; o >= 1; o >>= 1) v += __shfl_xor(v, o, 64);
        if (tid == 0) out[b] = v + bf[0];
    }
}

extern "C" void kernel_launch(void* const* d_in, const int* in_sizes, int n_in,
                              void* d_out, int out_size, void* d_ws, size_t ws_size,
                              hipStream_t stream) {
    const float* x    = (const float*)d_in[0];
    const float* edge = (const float*)d_in[1];
    const float* adj  = (const float*)d_in[2];
    const float* W_emb= (const float*)d_in[3];
    const float* b_emb= (const float*)d_in[4];
    const float* W1   = (const float*)d_in[5];
    const float* b1   = (const float*)d_in[6];
    const float* W2   = (const float*)d_in[7];
    const float* b2   = (const float*)d_in[8];
    const float* gWi  = (const float*)d_in[9];
    const float* gWh  = (const float*)d_in[10];
    const float* gbi  = (const float*)d_in[11];
    const float* gbh  = (const float*)d_in[12];
    const float* lWi  = (const float*)d_in[13];
    const float* lWh  = (const float*)d_in[14];
    const float* lbi  = (const float*)d_in[15];
    const float* lbh  = (const float*)d_in[16];
    const float* Wf   = (const float*)d_in[17];
    const float* bf   = (const float*)d_in[18];
    float* out = (float*)d_out;

    __hip_bfloat16* taT2  = (__hip_bfloat16*)d_ws;      // 8388608 bf16
    __hip_bfloat16* W2FTB = taT2 + 8388608;             // 131072 bf16
    short* hTg  = (short*)(W2FTB + 131072);             // 65536 bf16
    float* hG   = (float*)(hTg + 65536);                // 65536 f32
    float* mskp = hG + 65536;                           // 2048 f32
    float* partial = mskp + 2048;                       // 262144 f32
    float* gWiT = partial + 262144;                     // 3072
    float* gWhT = gWiT + 3072;                          // 3072
    float* b2T  = gWhT + 3072;                          // 1024
    float* lWiT = b2T + 1024;                           // 8192
    float* lWhT = lWiT + 8192;                          // 4096
    int*   cnt  = (int*)(lWhT + 4096);                  // 192 int

    k_prep<<<2048, 256, 0, stream>>>(edge, adj, W1, b1, x, W_emb, b_emb, W2,
                                     gWi, gWh, b2, lWi, lWh,
                                     taT2, W2FTB, hG, hTg, mskp,
                                     gWiT, gWhT, b2T, lWiT, lWhT, cnt);
    for (int l = 0; l < 3; ++l) {
        k_layer<<<256, 256, 0, stream>>>(taT2, W2FTB, hG, hTg, adj, mskp,
                                         gWiT, gWhT, b2T, gbi, gbh,
                                         lWiT, lWhT, lbi, lbh, Wf, bf,
                                         partial, cnt + l * 64, out,
                                         (l == 2) ? 1 : 0);
    }
}

// Round 15
// 108.101 us; speedup vs baseline: 3.9913x; 3.9913x over previous
//
#include <hip/hip_runtime.h>
#include <hip/hip_bf16.h>
#include <math.h>

typedef __attribute__((ext_vector_type(8))) short bf16x8;
typedef __attribute__((ext_vector_type(16))) float f32x16;

__device__ __forceinline__ float sigf(float x) { return 1.0f / (1.0f + expf(-x)); }

// prep: taT2[b][j][c][i] (bf16), h (f32), hTg (bf16 [b][v][node]), msk,
//       W2FTB blocked [cv>>4][u][cv&15], transposed small weights.
// grid = 2048 (b = bid>>5, j = bid&31) x 256 thr.
__global__ __launch_bounds__(256, 4) void k_prep(
    const float* __restrict__ edge, const float* __restrict__ adj,
    const float* __restrict__ W1, const float* __restrict__ b1,
    const float* __restrict__ x, const float* __restrict__ W_emb,
    const float* __restrict__ b_emb, const float* __restrict__ W2,
    const float* __restrict__ gWi, const float* __restrict__ gWh,
    const float* __restrict__ b2, const float* __restrict__ lWi,
    const float* __restrict__ lWh,
    __hip_bfloat16* __restrict__ taT2, __hip_bfloat16* __restrict__ W2FTB,
    float* __restrict__ h, short* __restrict__ hTg, float* __restrict__ msk,
    float* __restrict__ gWiT, float* __restrict__ gWhT, float* __restrict__ b2T,
    float* __restrict__ lWiT, float* __restrict__ lWhT) {
    __shared__ float es[512];       // [i][k] 32x16
    __shared__ float adjv[32];
    __shared__ float xs[256];
    __shared__ short t_lds[4096];   // [c][i]
    const int tid = threadIdx.x, bid = blockIdx.x;
    const int b = bid >> 5, j = bid & 31;
    const int c = tid & 127, g = tid >> 7;
    float wr[16];
    #pragma unroll
    for (int v = 0; v < 16; ++v) wr[v] = W1[v * 128 + c];
    const float b1c = b1[c];
    if (tid < 128) {
        int i = tid >> 2, k4 = tid & 3;
        ((float4*)es)[tid] = *(const float4*)&edge[(((long)(b * 32 + i)) * 32 + j) * 16 + k4 * 4];
    } else if (tid < 160) {
        int i = tid - 128;
        adjv[i] = adj[(b * 32 + i) * 32 + j];
    }
    if (bid < 256) xs[tid] = x[bid * 256 + tid];
    __syncthreads();
    {   // edge MLP for i = g*16 .. +15, col c -> t_lds[c][i]
        #pragma unroll
        for (int ii = 0; ii < 16; ++ii) {
            int i = g * 16 + ii;
            const float* er = es + i * 16;
            float acc = b1c;
            #pragma unroll
            for (int k = 0; k < 16; ++k) acc += er[k] * wr[k];
            float val = adjv[i] * fmaxf(acc, 0.f);
            t_lds[c * 32 + i] = (short)__bfloat16_as_ushort(__float2bfloat16(val));
        }
    }
    __syncthreads();
    {   // coalesced copy out
        int4* dst = (int4*)(taT2 + (long)bid * 4096);
        const int4* src = (const int4*)t_lds;
        dst[tid] = src[tid];
        dst[tid + 256] = src[tid + 256];
    }
    if (bid < 256) {            // embed: 8 rows of (b*N+n)
        int r = tid >> 5, u = tid & 31;
        int rowe = bid * 8 + r;
        float acc = b_emb[u];
        #pragma unroll
        for (int k = 0; k < 32; ++k) acc += xs[r * 32 + k] * W_emb[k * 32 + u];
        h[rowe * 32 + u] = acc;
        hTg[(rowe >> 5) * 1024 + u * 32 + (rowe & 31)] =
            (short)__bfloat16_as_ushort(__float2bfloat16(acc));
        if (u == 0) {
            float s = 0.f;
            #pragma unroll
            for (int k = 0; k < 32; ++k) s += xs[r * 32 + k];
            msk[rowe] = (s > 0.f) ? 1.f : 0.f;
        }
    } else if (bid < 384) {     // W2FTB
        int base = (bid - 256) * 1024;
        #pragma unroll
        for (int q = 0; q < 4; ++q) {
            int idx = base + q * 256 + tid;
            int chunk = idx >> 9, u = (idx >> 4) & 31, inner = idx & 15;
            int cv = chunk * 16 + inner;
            int cc = cv >> 5, v = cv & 31;
            W2FTB[idx] = __float2bfloat16(W2[cc * 1024 + u * 32 + v]);
        }
    } else if (bid == 384) {    // transposed weights
        for (int idx = tid; idx < 3072; idx += 256) gWiT[(idx & 31) * 96 + (idx >> 5)] = gWi[idx];
        for (int idx = tid; idx < 3072; idx += 256) gWhT[(idx & 31) * 96 + (idx >> 5)] = gWh[idx];
        for (int idx = tid; idx < 1024; idx += 256) b2T[(idx & 31) * 32 + (idx >> 5)] = b2[idx];
        for (int idx = tid; idx < 8192; idx += 256) lWiT[(idx & 63) * 128 + (idx >> 6)] = lWi[idx];
        for (int idx = tid; idx < 4096; idx += 256) lWhT[(idx & 31) * 128 + (idx >> 5)] = lWh[idx];
    }
}

// one layer: grid 256 = (b = bid>>2, jc = bid&3) x 256 thr (4 waves).
// Block owns 8 j's end-to-end: GEMM1 P[j][4096] in LDS, GEMM2 (K wave-split),
// GRU for those j's. No cross-block dependency inside a dispatch.
__global__ __launch_bounds__(256, 2) void k_layer(
    const __hip_bfloat16* __restrict__ taT2, const __hip_bfloat16* __restrict__ W2FTB,
    const float* __restrict__ hin, const short* __restrict__ hTin,
    float* __restrict__ hout, short* __restrict__ hTout,
    const float* __restrict__ adj, const float* __restrict__ msk,
    const float* __restrict__ gWiT, const float* __restrict__ gWhT,
    const float* __restrict__ b2T, const float* __restrict__ gbi,
    const float* __restrict__ gbh) {
    __shared__ __align__(16) char P_lds[65536];   // P[j<8][cv<4096] bf16, swizzled
    __shared__ __align__(16) short hT[1024];      // [v][i]
    __shared__ float hsh[1024], adjs[1024];
    __shared__ float hsumL[256], gbs[192], mskk[32];
    const int tid = threadIdx.x, bid = blockIdx.x;
    const int b = bid >> 2, jc = bid & 3;
    const int w = tid >> 6, l = tid & 63, lid = l & 31, kh = l >> 5;

    if (tid < 128) ((int4*)hT)[tid] = ((const int4*)(hTin + b * 1024))[tid];
    for (int k = tid; k < 1024; k += 256) { hsh[k] = hin[b * 1024 + k]; adjs[k] = adj[b * 1024 + k]; }
    if (tid < 96) gbs[tid] = gbi[tid];
    else if (tid < 192) gbs[tid] = gbh[tid - 96];
    if (tid < 32) mskk[tid] = msk[b * 32 + tid];
    __syncthreads();

    const short* taB = (const short*)taT2 + (long)b * 131072 + jc * 8 * 128 * 32;
    const short* w2b = (const short*)W2FTB;
    const short* hTp = hT + lid * 32 + kh * 8;
    bf16x8 hb0 = *(const bf16x8*)hTp;          // B: col=v=lid, k=i=kh*8+e
    bf16x8 hb1 = *(const bf16x8*)(hTp + 16);
    // ---- GEMM1: tile t = w*8+q -> jj = t>>2, c in [(t&3)*32, +32) ----
    #pragma unroll 2
    for (int q = 0; q < 8; ++q) {
        int t = w * 8 + q;
        int jj = t >> 2, cbase = (t & 3) * 32;
        const short* ap = taB + ((jj * 128 + cbase + lid) * 32 + kh * 8);
        bf16x8 a0 = *(const bf16x8*)ap;
        bf16x8 a1 = *(const bf16x8*)(ap + 16);
        f32x16 accg = {};
        accg = __builtin_amdgcn_mfma_f32_32x32x16_bf16(a0, hb0, accg, 0, 0, 0);
        accg = __builtin_amdgcn_mfma_f32_32x32x16_bf16(a1, hb1, accg, 0, 0, 0);
        #pragma unroll
        for (int r = 0; r < 16; ++r) {
            int crow = (r & 3) + 8 * (r >> 2) + 4 * kh;   // c local
            int byte = (jj * 8192 + (cbase + crow) * 64 + lid * 2) ^ (jj << 4);
            *(short*)(P_lds + byte) =
                (short)__bfloat16_as_ushort(__float2bfloat16(accg[r]));
        }
    }
    __syncthreads();
    // ---- GEMM2: wave w covers cv in [w*1024, +1024); A rows = j (8 real) ----
    f32x16 acc = {};
    const int jloc = lid & 7;
    #pragma unroll 4
    for (int step = 0; step < 64; ++step) {
        // full byte offset computed FIRST, XOR applied LAST (matches store side;
        // R14 bug: XOR-then-add carried kh*16 into bit 5 for odd jloc -> garbage reads)
        int abyte = (jloc * 8192 + w * 2048 + step * 32 + kh * 16) ^ (jloc << 4);
        bf16x8 a = *(const bf16x8*)(P_lds + abyte);
        bf16x8 bg = *(const bf16x8*)(w2b + (w * 64 + step) * 512 + lid * 16 + kh * 8);
        acc = __builtin_amdgcn_mfma_f32_32x32x16_bf16(a, bg, acc, 0, 0, 0);
    }
    __syncthreads();
    // ---- mred + GRU-weight staging (alias P_lds; all P reads done) ----
    float* mred = (float*)P_lds;            // [4][8][32]
    float* wWiT = (float*)P_lds + 1024;     // [v*96+k]
    float* wWhT = (float*)P_lds + 4096;
    float* b2s  = (float*)P_lds + 7168;     // [v*32+u]
    float* mLs  = (float*)P_lds + 8192;     // [j8*32+u]
    #pragma unroll
    for (int r = 0; r < 4; ++r)             // valid C rows: crow = r + 4*kh < 8
        mred[w * 256 + (4 * kh + r) * 32 + lid] = acc[r];
    for (int k = tid; k < 3072; k += 256) { wWiT[k] = gWiT[k]; wWhT[k] = gWhT[k]; }
    for (int k = tid; k < 1024; k += 256) b2s[k] = b2T[k];
    __syncthreads();
    const int j8 = tid >> 5, u = tid & 31, jg = jc * 8 + j8;
    float msum = mred[j8 * 32 + u] + mred[256 + j8 * 32 + u]
               + mred[512 + j8 * 32 + u] + mred[768 + j8 * 32 + u];
    float hs = 0.f;     // hsum[jg][u] = sum_i adj[b,i,jg]*h[b,i,u]
    #pragma unroll
    for (int i = 0; i < 32; ++i) hs += adjs[i * 32 + jg] * hsh[i * 32 + u];
    hsumL[tid] = hs;
    __syncthreads();
    float m = msum;
    #pragma unroll
    for (int v = 0; v < 32; ++v) m += b2s[v * 32 + u] * hsumL[j8 * 32 + v];
    mLs[j8 * 32 + u] = m;
    __syncthreads();
    float gi[3], gh[3];
    #pragma unroll
    for (int kb = 0; kb < 3; ++kb) {
        int k = kb * 32 + u;
        float a = gbs[k], cgh = gbs[96 + k];
        #pragma unroll
        for (int v = 0; v < 32; ++v) {
            a   += mLs[j8 * 32 + v] * wWiT[v * 96 + k];
            cgh += hsh[jg * 32 + v] * wWhT[v * 96 + k];
        }
        gi[kb] = a; gh[kb] = cgh;
    }
    float r = sigf(gi[0] + gh[0]);
    float z = sigf(gi[1] + gh[1]);
    float n = tanhf(gi[2] + r * gh[2]);
    float hv = hsh[jg * 32 + u];
    float res = mskk[jg] * ((1.f - z) * n + z * hv);
    hout[b * 1024 + jg * 32 + u] = res;
    hTout[b * 1024 + u * 32 + jg] = (short)__bfloat16_as_ushort(__float2bfloat16(res));
}

// Set2Set + final fc. grid = B, block = 128.
__global__ __launch_bounds__(128, 4) void k_s2s(
    const float* __restrict__ h, const float* __restrict__ msk,
    const float* __restrict__ lWiT, const float* __restrict__ lWhT,
    const float* __restrict__ lbi, const float* __restrict__ lbh,
    const float* __restrict__ Wf, const float* __restrict__ bf,
    float* __restrict__ out) {
    __shared__ float hsh[1024];
    __shared__ float mskk[32], qs[32], cs2[32], qstar[64], gsv[128], asv[32];
    const int tid = threadIdx.x, b = blockIdx.x;
    for (int k = tid; k < 1024; k += 128) hsh[k] = h[b * 1024 + k];
    if (tid < 32) { mskk[tid] = msk[b * 32 + tid]; qs[tid] = 0.f; cs2[tid] = 0.f; }
    if (tid < 64) qstar[tid] = 0.f;
    __syncthreads();
    for (int step = 0; step < 3; ++step) {
        {
            float g = lbi[tid] + lbh[tid];
            #pragma unroll
            for (int pp = 0; pp < 64; ++pp) g += qstar[pp] * lWiT[pp * 128 + tid];
            #pragma unroll
            for (int v = 0; v < 32; ++v) g += qs[v] * lWhT[v * 128 + tid];
            gsv[tid] = g;
        }
        __syncthreads();
        if (tid < 32) {
            float ci = sigf(gsv[32 + tid]) * cs2[tid] + sigf(gsv[tid]) * tanhf(gsv[64 + tid]);
            cs2[tid] = ci;
            qs[tid] = sigf(gsv[96 + tid]) * tanhf(ci);
        }
        __syncthreads();
        if (tid < 32) {
            float e = 0.f;
            #pragma unroll
            for (int v = 0; v < 32; ++v) e += hsh[tid * 32 + v] * qs[v];
            e = (mskk[tid] == 0.f) ? -INFINITY : e;
            float mx = e;
            for (int o = 16; o >= 1; o >>= 1) mx = fmaxf(mx, __shfl_xor(mx, o, 64));
            float a = expf(e - mx);
            float ss = a;
            for (int o = 16; o >= 1; o >>= 1) ss += __shfl_xor(ss, o, 64);
            asv[tid] = a / ss;
        }
        __syncthreads();
        if (tid < 32) {
            float rr = 0.f;
            #pragma unroll
            for (int nn = 0; nn < 32; ++nn) rr += asv[nn] * hsh[nn * 32 + tid] * mskk[nn];
            qstar[tid] = qs[tid];
            qstar[32 + tid] = rr;
        }
        __syncthreads();
    }
    if (tid < 64) {
        float v = qstar[tid] * Wf[tid];
        for (int o = 32; o >= 1; o >>= 1) v += __shfl_xor(v, o, 64);
        if (tid == 0) out[b] = v + bf[0];
    }
}

extern "C" void kernel_launch(void* const* d_in, const int* in_sizes, int n_in,
                              void* d_out, int out_size, void* d_ws, size_t ws_size,
                              hipStream_t stream) {
    const float* x    = (const float*)d_in[0];
    const float* edge = (const float*)d_in[1];
    const float* adj  = (const float*)d_in[2];
    const float* W_emb= (const float*)d_in[3];
    const float* b_emb= (const float*)d_in[4];
    const float* W1   = (const float*)d_in[5];
    const float* b1   = (const float*)d_in[6];
    const float* W2   = (const float*)d_in[7];
    const float* b2   = (const float*)d_in[8];
    const float* gWi  = (const float*)d_in[9];
    const float* gWh  = (const float*)d_in[10];
    const float* gbi  = (const float*)d_in[11];
    const float* gbh  = (const float*)d_in[12];
    const float* lWi  = (const float*)d_in[13];
    const float* lWh  = (const float*)d_in[14];
    const float* lbi  = (const float*)d_in[15];
    const float* lbh  = (const float*)d_in[16];
    const float* Wf   = (const float*)d_in[17];
    const float* bf   = (const float*)d_in[18];
    float* out = (float*)d_out;

    __hip_bfloat16* taT2  = (__hip_bfloat16*)d_ws;      // 8388608 bf16
    __hip_bfloat16* W2FTB = taT2 + 8388608;             // 131072 bf16
    short* hTgA = (short*)(W2FTB + 131072);             // 65536 bf16
    short* hTgB = hTgA + 65536;                         // 65536 bf16
    float* hA   = (float*)(hTgB + 65536);               // 65536 f32
    float* hB   = hA + 65536;                           // 65536 f32
    float* mskp = hB + 65536;                           // 2048 f32
    float* gWiT = mskp + 2048;                          // 3072
    float* gWhT = gWiT + 3072;                          // 3072
    float* b2T  = gWhT + 3072;                          // 1024
    float* lWiT = b2T + 1024;                           // 8192
    float* lWhT = lWiT + 8192;                          // 4096

    k_prep<<<2048, 256, 0, stream>>>(edge, adj, W1, b1, x, W_emb, b_emb, W2,
                                     gWi, gWh, b2, lWi, lWh,
                                     taT2, W2FTB, hA, hTgA, mskp,
                                     gWiT, gWhT, b2T, lWiT, lWhT);
    float* hcur = hA; float* hnxt = hB;
    short* hTcur = hTgA; short* hTnxt = hTgB;
    for (int l = 0; l < 3; ++l) {
        k_layer<<<256, 256, 0, stream>>>(taT2, W2FTB, hcur, hTcur, hnxt, hTnxt,
                                         adj, mskp, gWiT, gWhT, b2T, gbi, gbh);
        float* tf = hcur; hcur = hnxt; hnxt = tf;
        short* ts = hTcur; hTcur = hTnxt; hTnxt = ts;
    }
    k_s2s<<<64, 128, 0, stream>>>(hcur, mskp, lWiT, lWhT, lbi, lbh, Wf, bf, out);
}

// Round 16
// 104.780 us; speedup vs baseline: 4.1178x; 1.0317x over previous
//
#include <hip/hip_runtime.h>
#include <hip/hip_bf16.h>
#include <math.h>

typedef __attribute__((ext_vector_type(8))) short bf16x8;
typedef __attribute__((ext_vector_type(16))) float f32x16;

__device__ __forceinline__ float sigf(float x) { return 1.0f / (1.0f + expf(-x)); }
// P-layout swizzle (R13-proven): fold byte bits 9,10,13 into bank bits 4,5,6
__device__ __forceinline__ int swz(int b) { return b ^ ((b >> 5) & 0x30) ^ ((b >> 7) & 0x40); }

// prep: taT2[b][j][c][i] (bf16), h (f32), msk, W2FTB blocked, gWiT/gWhT/b2T.
// grid = 2048 (b = bid>>5, j = bid&31) x 256 thr.
__global__ __launch_bounds__(256, 4) void k_prep(
    const float* __restrict__ edge, const float* __restrict__ adj,
    const float* __restrict__ W1, const float* __restrict__ b1,
    const float* __restrict__ x, const float* __restrict__ W_emb,
    const float* __restrict__ b_emb, const float* __restrict__ W2,
    const float* __restrict__ gWi, const float* __restrict__ gWh,
    const float* __restrict__ b2,
    __hip_bfloat16* __restrict__ taT2, __hip_bfloat16* __restrict__ W2FTB,
    float* __restrict__ h, float* __restrict__ msk,
    float* __restrict__ gWiT, float* __restrict__ gWhT, float* __restrict__ b2T) {
    __shared__ float es[512];       // [i][k] 32x16
    __shared__ float adjv[32];
    __shared__ float xs[256];
    __shared__ short t_lds[4096];   // [c][i]
    const int tid = threadIdx.x, bid = blockIdx.x;
    const int b = bid >> 5, j = bid & 31;
    const int c = tid & 127, g = tid >> 7;
    float wr[16];
    #pragma unroll
    for (int v = 0; v < 16; ++v) wr[v] = W1[v * 128 + c];
    const float b1c = b1[c];
    if (tid < 128) {
        int i = tid >> 2, k4 = tid & 3;
        ((float4*)es)[tid] = *(const float4*)&edge[(((long)(b * 32 + i)) * 32 + j) * 16 + k4 * 4];
    } else if (tid < 160) {
        int i = tid - 128;
        adjv[i] = adj[(b * 32 + i) * 32 + j];
    }
    if (bid < 256) xs[tid] = x[bid * 256 + tid];
    __syncthreads();
    {   // edge MLP for i = g*16 .. +15, col c -> t_lds[c][i]
        #pragma unroll
        for (int ii = 0; ii < 16; ++ii) {
            int i = g * 16 + ii;
            const float* er = es + i * 16;
            float acc = b1c;
            #pragma unroll
            for (int k = 0; k < 16; ++k) acc += er[k] * wr[k];
            float val = adjv[i] * fmaxf(acc, 0.f);
            t_lds[c * 32 + i] = (short)__bfloat16_as_ushort(__float2bfloat16(val));
        }
    }
    __syncthreads();
    {   // coalesced copy out
        int4* dst = (int4*)(taT2 + (long)bid * 4096);
        const int4* src = (const int4*)t_lds;
        dst[tid] = src[tid];
        dst[tid + 256] = src[tid + 256];
    }
    if (bid < 256) {            // embed: 8 rows of (b*N+n)
        int r = tid >> 5, u = tid & 31;
        int rowe = bid * 8 + r;
        float acc = b_emb[u];
        #pragma unroll
        for (int k = 0; k < 32; ++k) acc += xs[r * 32 + k] * W_emb[k * 32 + u];
        h[rowe * 32 + u] = acc;
        if (u == 0) {
            float s = 0.f;
            #pragma unroll
            for (int k = 0; k < 32; ++k) s += xs[r * 32 + k];
            msk[rowe] = (s > 0.f) ? 1.f : 0.f;
        }
    } else if (bid < 384) {     // W2FTB
        int base = (bid - 256) * 1024;
        #pragma unroll
        for (int q = 0; q < 4; ++q) {
            int idx = base + q * 256 + tid;
            int chunk = idx >> 9, u = (idx >> 4) & 31, inner = idx & 15;
            int cv = chunk * 16 + inner;
            int cc = cv >> 5, v = cv & 31;
            W2FTB[idx] = __float2bfloat16(W2[cc * 1024 + u * 32 + v]);
        }
    } else if (bid == 384) {    // transposed GRU weights
        for (int idx = tid; idx < 3072; idx += 256) gWiT[(idx & 31) * 96 + (idx >> 5)] = gWi[idx];
        for (int idx = tid; idx < 3072; idx += 256) gWhT[(idx & 31) * 96 + (idx >> 5)] = gWh[idx];
        for (int idx = tid; idx < 1024; idx += 256) b2T[(idx & 31) * 32 + (idx >> 5)] = b2[idx];
    }
}

// msg: grid 256 = (b = bid>>2, cq = bid&3), 256 thr (4 waves). Dense GEMMs.
// GEMM1: P_chunk[j][clocal][v] -> LDS (swizzled); GEMM2: partial_m -> partial.
__global__ __launch_bounds__(256, 2) void k_msg(
    const __hip_bfloat16* __restrict__ taT2, const __hip_bfloat16* __restrict__ W2FTB,
    const float* __restrict__ h, float* __restrict__ partial) {
    __shared__ __align__(16) char P_lds[65536];
    __shared__ __align__(16) short hT[1024];     // [v][i]
    const int tid = threadIdx.x, bid = blockIdx.x;
    const int b = bid >> 2, cq = bid & 3;
    const int w = tid >> 6, l = tid & 63, lid = l & 31, kh = l >> 5;
    for (int idx = tid; idx < 1024; idx += 256)
        hT[(idx & 31) * 32 + (idx >> 5)] =
            (short)__bfloat16_as_ushort(__float2bfloat16(h[b * 1024 + idx]));
    __syncthreads();
    const short* taB = (const short*)taT2 + (long)b * 131072;
    const short* w2b = (const short*)W2FTB;
    const short* hTp = hT + lid * 32 + kh * 8;
    bf16x8 hb0 = *(const bf16x8*)hTp;          // B: col=v=lid, k=i=kh*8+e
    bf16x8 hb1 = *(const bf16x8*)(hTp + 16);
    // ---- GEMM1: wave w computes j = w*8 .. +7 ----
    #pragma unroll 2
    for (int q = 0; q < 8; ++q) {
        int jj = w * 8 + q;
        const short* ap = taB + ((jj * 128 + cq * 32 + lid) * 32 + kh * 8);
        bf16x8 a0 = *(const bf16x8*)ap;
        bf16x8 a1 = *(const bf16x8*)(ap + 16);
        f32x16 accg = {};
        accg = __builtin_amdgcn_mfma_f32_32x32x16_bf16(a0, hb0, accg, 0, 0, 0);
        accg = __builtin_amdgcn_mfma_f32_32x32x16_bf16(a1, hb1, accg, 0, 0, 0);
        #pragma unroll
        for (int r = 0; r < 16; ++r) {
            int crow = (r & 3) + 8 * (r >> 2) + 4 * kh;   // clocal
            int byte = (crow * 2 + (lid >> 4)) * 1024 + ((lid >> 3) & 1) * 512
                     + jj * 16 + (lid & 7) * 2;
            *(short*)(P_lds + swz(byte)) =
                (short)__bfloat16_as_ushort(__float2bfloat16(accg[r]));
        }
    }
    __syncthreads();
    // ---- GEMM2: wave w covers slices w*16 .. +15 ----
    f32x16 acc = {};
    #pragma unroll
    for (int kk = 0; kk < 16; ++kk) {
        int slice = w * 16 + kk;
        bf16x8 a = *(const bf16x8*)(P_lds + swz(slice * 1024 + kh * 512 + lid * 16));
        bf16x8 bg = *(const bf16x8*)(w2b + (cq * 64 + slice) * 512 + lid * 16 + kh * 8);
        acc = __builtin_amdgcn_mfma_f32_32x32x16_bf16(a, bg, acc, 0, 0, 0);
    }
    __syncthreads();   // P reads done before red overwrites
    {
        float* red = (float*)P_lds + w * 1024;
        #pragma unroll
        for (int r = 0; r < 16; ++r) {
            int crow = (r & 3) + 8 * (r >> 2) + 4 * kh;   // = j
            red[crow * 32 + lid] = acc[r];
        }
    }
    __syncthreads();
    {
        float* r0 = (float*)P_lds;
        for (int k = tid; k < 1024; k += 256)
            partial[(long)bid * 1024 + k] = r0[k] + r0[1024 + k] + r0[2048 + k] + r0[3072 + k];
    }
}

// GRU layers 0,1: 256 blocks (b = bid>>2, jc = bid&3) x 256 thr; LDS-staged.
__global__ __launch_bounds__(256, 2) void k_gru(
    const float* __restrict__ partial, const float* __restrict__ h,
    const float* __restrict__ adj, const float* __restrict__ msk,
    const float* __restrict__ b2T, const float* __restrict__ gWiT,
    const float* __restrict__ gWhT, const float* __restrict__ gbi,
    const float* __restrict__ gbh, float* __restrict__ hout) {
    __shared__ float hsh[1024], adjs[1024], wWiT[3072], wWhT[3072], b2s[1024];
    __shared__ float hsumL[256], mLs[256], gbs[192];
    const int tid = threadIdx.x, bid = blockIdx.x;
    const int b = bid >> 2, jc = bid & 3;
    const int j8 = tid >> 5, u = tid & 31, jg = jc * 8 + j8;
    for (int k = tid; k < 1024; k += 256) hsh[k] = h[b * 1024 + k];
    for (int k = tid; k < 1024; k += 256) adjs[k] = adj[b * 1024 + k];
    for (int k = tid; k < 3072; k += 256) wWiT[k] = gWiT[k];
    for (int k = tid; k < 3072; k += 256) wWhT[k] = gWhT[k];
    for (int k = tid; k < 1024; k += 256) b2s[k] = b2T[k];
    if (tid < 96) gbs[tid] = gbi[tid];
    else if (tid < 192) gbs[tid] = gbh[tid - 96];
    float ps = 0.f;
    #pragma unroll
    for (int cq = 0; cq < 4; ++cq)
        ps += partial[((long)(b * 4 + cq)) * 1024 + jc * 256 + tid];
    __syncthreads();
    float hs = 0.f;
    #pragma unroll
    for (int i = 0; i < 32; ++i) hs += adjs[i * 32 + jg] * hsh[i * 32 + u];
    hsumL[tid] = hs;
    __syncthreads();
    float m = ps;
    #pragma unroll
    for (int v = 0; v < 32; ++v) m += b2s[v * 32 + u] * hsumL[j8 * 32 + v];
    mLs[tid] = m;
    __syncthreads();
    float gi[3], gh[3];
    #pragma unroll
    for (int kb = 0; kb < 3; ++kb) {
        int k = kb * 32 + u;
        float a = gbs[k], c = gbs[96 + k];
        #pragma unroll
        for (int v = 0; v < 32; ++v) {
            a += mLs[j8 * 32 + v] * wWiT[v * 96 + k];
            c += hsh[jg * 32 + v] * wWhT[v * 96 + k];
        }
        gi[kb] = a; gh[kb] = c;
    }
    float r = sigf(gi[0] + gh[0]);
    float z = sigf(gi[1] + gh[1]);
    float n = tanhf(gi[2] + r * gh[2]);
    float hv = hsh[jg * 32 + u];
    float mm = msk[b * 32 + jg];
    hout[b * 1024 + jg * 32 + u] = mm * ((1.f - z) * n + z * hv);
}

// final layer: GRU + Set2Set + fc. grid = 64 x 1024 thr (R10 GRU body + R4 s2s fusion).
__global__ __launch_bounds__(1024, 1) void k_gru_final(
    const float* __restrict__ partial, const float* __restrict__ h,
    const float* __restrict__ adj, const float* __restrict__ msk,
    const float* __restrict__ gWi, const float* __restrict__ gWh,
    const float* __restrict__ gbi, const float* __restrict__ gbh,
    const float* __restrict__ b2,
    const float* __restrict__ lWi, const float* __restrict__ lWh,
    const float* __restrict__ lbi, const float* __restrict__ lbh,
    const float* __restrict__ Wf, const float* __restrict__ bf,
    float* __restrict__ out) {
    __shared__ float hsh[1024], adjs[1024];
    __shared__ float wWiT[3104], wWhT[3104];   // [v*97+k]
    __shared__ float b2s[1056];                // [v*33+u]
    __shared__ float gbs[192];
    __shared__ float hsumL[1024], mLs[1024];
    __shared__ float mskk[32], qs[32], cs2[32], qstar[64], gsv[128], asv[32];
    const int tid = threadIdx.x, b = blockIdx.x;
    const int j = tid >> 5, u = tid & 31;
    {   // stage (R10-proven at 1024 thr)
        hsh[tid] = h[b * 1024 + tid];
        adjs[tid] = adj[b * 1024 + tid];
        if (tid < 32) mskk[tid] = msk[b * 32 + tid];
        for (int idx = tid; idx < 3072; idx += 1024)
            wWiT[(idx & 31) * 97 + (idx >> 5)] = gWi[idx];
        for (int idx = tid; idx < 3072; idx += 1024)
            wWhT[(idx & 31) * 97 + (idx >> 5)] = gWh[idx];
        if (tid < 96) gbs[tid] = gbi[tid];
        else if (tid < 192) gbs[tid] = gbh[tid - 96];
        b2s[(tid & 31) * 33 + (tid >> 5)] = b2[tid];
    }
    float ps = 0.f;
    #pragma unroll
    for (int cq = 0; cq < 4; ++cq)
        ps += partial[((long)(b * 4 + cq)) * 1024 + tid];
    __syncthreads();
    float hs = 0.f;
    #pragma unroll
    for (int i = 0; i < 32; ++i) hs += adjs[i * 32 + j] * hsh[i * 32 + u];
    hsumL[tid] = hs;
    __syncthreads();
    float m = ps;
    #pragma unroll
    for (int v = 0; v < 32; ++v) m += b2s[v * 33 + u] * hsumL[j * 32 + v];
    mLs[tid] = m;
    __syncthreads();
    float gi[3], gh[3];
    #pragma unroll
    for (int kb = 0; kb < 3; ++kb) {
        int k = kb * 32 + u;
        float a = gbs[k], cgh = gbs[96 + k];
        #pragma unroll
        for (int v = 0; v < 32; ++v) {
            a   += mLs[j * 32 + v] * wWiT[v * 97 + k];
            cgh += hsh[j * 32 + v] * wWhT[v * 97 + k];
        }
        gi[kb] = a; gh[kb] = cgh;
    }
    float r = sigf(gi[0] + gh[0]);
    float z = sigf(gi[1] + gh[1]);
    float n = tanhf(gi[2] + r * gh[2]);
    float hv = hsh[tid];
    float res = mskk[j] * ((1.f - z) * n + z * hv);
    hsumL[tid] = res;                 // h_new lives in hsumL (R4-proven pattern)
    float* hn = hsumL;
    if (tid < 64) { qstar[tid] = 0.f; if (tid < 32) { qs[tid] = 0.f; cs2[tid] = 0.f; } }
    __syncthreads();
    for (int step = 0; step < 3; ++step) {
        if (tid < 128) {
            float g = lbi[tid] + lbh[tid];
            #pragma unroll
            for (int pp = 0; pp < 64; ++pp) g += qstar[pp] * lWi[tid * 64 + pp];
            #pragma unroll
            for (int v = 0; v < 32; ++v) g += qs[v] * lWh[tid * 32 + v];
            gsv[tid] = g;
        }
        __syncthreads();
        if (tid < 32) {
            float ci = sigf(gsv[32 + tid]) * cs2[tid] + sigf(gsv[tid]) * tanhf(gsv[64 + tid]);
            cs2[tid] = ci;
            qs[tid] = sigf(gsv[96 + tid]) * tanhf(ci);
        }
        __syncthreads();
        if (tid < 32) {
            float e = 0.f;
            #pragma unroll
            for (int v = 0; v < 32; ++v) e += hn[tid * 32 + v] * qs[v];
            e = (mskk[tid] == 0.f) ? -INFINITY : e;
            float mx = e;
            for (int o = 16; o >= 1; o >>= 1) mx = fmaxf(mx, __shfl_xor(mx, o, 64));
            float a = expf(e - mx);
            float ss = a;
            for (int o = 16; o >= 1; o >>= 1) ss += __shfl_xor(ss, o, 64);
            asv[tid] = a / ss;
        }
        __syncthreads();
        if (tid < 32) {
            float rr = 0.f;
            #pragma unroll
            for (int nn = 0; nn < 32; ++nn) rr += asv[nn] * hn[nn * 32 + tid] * mskk[nn];
            qstar[tid] = qs[tid];
            qstar[32 + tid] = rr;
        }
        __syncthreads();
    }
    if (tid < 64) {
        float v = qstar[tid] * Wf[tid];
        for (int o = 32; o >= 1; o >>= 1) v += __shfl_xor(v, o, 64);
        if (tid == 0) out[b] = v + bf[0];
    }
}

extern "C" void kernel_launch(void* const* d_in, const int* in_sizes, int n_in,
                              void* d_out, int out_size, void* d_ws, size_t ws_size,
                              hipStream_t stream) {
    const float* x    = (const float*)d_in[0];
    const float* edge = (const float*)d_in[1];
    const float* adj  = (const float*)d_in[2];
    const float* W_emb= (const float*)d_in[3];
    const float* b_emb= (const float*)d_in[4];
    const float* W1   = (const float*)d_in[5];
    const float* b1   = (const float*)d_in[6];
    const float* W2   = (const float*)d_in[7];
    const float* b2   = (const float*)d_in[8];
    const float* gWi  = (const float*)d_in[9];
    const float* gWh  = (const float*)d_in[10];
    const float* gbi  = (const float*)d_in[11];
    const float* gbh  = (const float*)d_in[12];
    const float* lWi  = (const float*)d_in[13];
    const float* lWh  = (const float*)d_in[14];
    const float* lbi  = (const float*)d_in[15];
    const float* lbh  = (const float*)d_in[16];
    const float* Wf   = (const float*)d_in[17];
    const float* bf   = (const float*)d_in[18];
    float* out = (float*)d_out;

    __hip_bfloat16* taT2  = (__hip_bfloat16*)d_ws;      // 8388608 bf16
    __hip_bfloat16* W2FTB = taT2 + 8388608;             // 131072 bf16
    float* hA   = (float*)(W2FTB + 131072);             // 65536 f32
    float* hB   = hA + 65536;                           // 65536 f32
    float* mskp = hB + 65536;                           // 2048 f32
    float* partial = mskp + 2048;                       // 262144 f32
    float* gWiT = partial + 262144;                     // 3072
    float* gWhT = gWiT + 3072;                          // 3072
    float* b2T  = gWhT + 3072;                          // 1024

    k_prep<<<2048, 256, 0, stream>>>(edge, adj, W1, b1, x, W_emb, b_emb, W2,
                                     gWi, gWh, b2,
                                     taT2, W2FTB, hA, mskp, gWiT, gWhT, b2T);
    float* hcur = hA; float* hnxt = hB;
    for (int l = 0; l < 2; ++l) {
        k_msg<<<256, 256, 0, stream>>>(taT2, W2FTB, hcur, partial);
        k_gru<<<256, 256, 0, stream>>>(partial, hcur, adj, mskp, b2T,
                                       gWiT, gWhT, gbi, gbh, hnxt);
        float* tf = hcur; hcur = hnxt; hnxt = tf;
    }
    k_msg<<<256, 256, 0, stream>>>(taT2, W2FTB, hcur, partial);
    k_gru_final<<<64, 1024, 0, stream>>>(partial, hcur, adj, mskp,
                                         gWi, gWh, gbi, gbh, b2,
                                         lWi, lWh, lbi, lbh, Wf, bf, out);
}